// Round 6
// baseline (120.380 us; speedup 1.0000x reference)
//
#include <hip/hip_runtime.h>
#include <hip/hip_bf16.h>
#include <math.h>

#define BATCH 2048
#define LATENT 64
#define LOG_2PI 1.8378770664093453f
#define BETA_M1 5.0f
#define LN2 0.69314718055994530942f
// C2 = -0.5 * log2(e)
#define C2 (-0.72134752044448170368f)

typedef float v2f __attribute__((ext_vector_type(2)));

// ws layout (float units):
//   PPS  f32 [64][2048]   per-(l,i) exp-sum accumulators (zeroed, atomicAdd)
//   CE   f32 [2048], KLP f32 [2048]
//   RMP/RSP f32 [2][2048] row-LSE partials (log2 domain)
//   PART f32 [16]         [0]=tc (atomic), [1]=kl (atomic)
//   BF   bf16 region:  VC[64][2048], VM[64][2048], TE[64][2048],
//                      UZ[64][2048] (z^2), UN[64][2048] (-2z)
#define OFF_PPS  0
#define OFF_CE   (OFF_PPS + 64*BATCH)
#define OFF_KLP  (OFF_CE + BATCH)
#define OFF_RMP  (OFF_KLP + BATCH)
#define OFF_RSP  (OFF_RMP + 2*BATCH)
#define OFF_PART (OFF_RSP + 2*BATCH)
#define OFF_BF   (OFF_PART + 16)
// bf16 sub-offsets (uint16 units from (uint16_t*)(ws+OFF_BF))
#define BO_VC 0
#define BO_VM (64*BATCH)
#define BO_TE (128*BATCH)
#define BO_UZ (192*BATCH)
#define BO_UN (256*BATCH)

__device__ inline uint16_t f2bf(float f) {
    uint32_t u = __float_as_uint(f);
    return (uint16_t)((u + 0x7FFFu + ((u >> 16) & 1u)) >> 16);
}
__device__ inline float bflo(uint32_t u) { return __uint_as_float(u << 16); }
__device__ inline float bfhi(uint32_t u) { return __uint_as_float(u & 0xFFFF0000u); }

// Precompute: grid 128 x 256, each block transposes 16 j x 64 l; writes bf16
// stages + f32 CE/KLP; zeroes PPS (4 floats/thread) and PART.
__global__ __launch_bounds__(256) void precompute_kernel(const float* __restrict__ z,
                                                         const float* __restrict__ zm,
                                                         const float* __restrict__ zlv,
                                                         float* __restrict__ ws) {
    __shared__ float Tz[16][65], Tm[16][65], Tlv[16][65];
    __shared__ float CEp[16][16], KLp[16][16];
    int t = threadIdx.x, lane = t & 63, w = t >> 6;
    int j0 = blockIdx.x * 16;

    // zero PPS slice: 128*256*4 = 131072 floats
    *(float4*)(ws + OFF_PPS + (blockIdx.x * 256 + t) * 4) = make_float4(0.f, 0.f, 0.f, 0.f);
    if (blockIdx.x == 0 && t < 16) ws[OFF_PART + t] = 0.0f;

    #pragma unroll
    for (int p = 0; p < 4; ++p) {
        int jr = p * 4 + w;
        int idx = (j0 + jr) * LATENT + lane;
        Tz[jr][lane]  = z[idx];
        Tm[jr][lane]  = zm[idx];
        Tlv[jr][lane] = zlv[idx];
    }
    __syncthreads();

    uint16_t* bfb = (uint16_t*)(ws + OFF_BF);
    int jl = t & 15, lg = t >> 4;
    int j = j0 + jl;
    float ce_acc = 0.0f, kl_acc = 0.0f;
    #pragma unroll
    for (int q = 0; q < 4; ++q) {
        int l = q * 16 + lg;
        float zv = Tz[jl][l];
        float m  = Tm[jl][l];
        float lv = Tlv[jl][l];
        float iv  = __expf(-lv);
        float civ = C2 * iv;
        float miv = m * iv;
        float cmv = C2 * miv;
        float cev = C2 * fmaf(m, miv, lv + LOG_2PI);
        bfb[BO_VC + l * BATCH + j] = f2bf(civ);
        bfb[BO_VM + l * BATCH + j] = f2bf(cmv);
        bfb[BO_TE + l * BATCH + j] = f2bf(cev);
        bfb[BO_UZ + l * BATCH + j] = f2bf(zv * zv);
        bfb[BO_UN + l * BATCH + j] = f2bf(-2.0f * zv);
        ce_acc += cev;
        kl_acc += fmaf(m, m, __expf(lv)) - lv - 1.0f;
    }
    CEp[lg][jl] = ce_acc;
    KLp[lg][jl] = kl_acc;
    __syncthreads();
    if (t < 16) {
        float ce = 0.0f, kl = 0.0f;
        #pragma unroll
        for (int g = 0; g < 16; ++g) { ce += CEp[g][t]; kl += KLp[g][t]; }
        ws[OFF_CE  + j0 + t] = ce;
        ws[OFF_KLP + j0 + t] = kl;
    }
}

// Fused main: blocks [0,512) dim path (l = bx>>3, 256-j chunk jc = bx&7,
// 8 i/thread packed as j-pairs), blocks [512,1024) row path.
#define DIMB 512
#define ROWB 512
__global__ __launch_bounds__(256) void main_kernel(float* __restrict__ ws) {
    __shared__ float RMs[8][4], RSs[8][4];
    int bx = blockIdx.x, t = threadIdx.x;
    const uint16_t* bfb = (const uint16_t*)(ws + OFF_BF);

    if (bx < DIMB) {
        int l  = bx >> 3;
        int jc = bx & 7;

        // per-thread 8 i values, splat into v2f pairs (packed over j)
        v2f z2p[8], n2p[8], sp[8];
        #pragma unroll
        for (int k = 0; k < 8; ++k) {
            float zz = bflo((uint32_t)bfb[BO_UZ + l * BATCH + t + 256 * k] << 16 >> 16
                            ? 0u : 0u); // placeholder avoided below
            (void)zz;
        }
        #pragma unroll
        for (int k = 0; k < 8; ++k) {
            float z2 = __uint_as_float((uint32_t)bfb[BO_UZ + l * BATCH + t + 256 * k] << 16);
            float n2 = __uint_as_float((uint32_t)bfb[BO_UN + l * BATCH + t + 256 * k] << 16);
            z2p[k] = z2;   // splat
            n2p[k] = n2;   // splat
            sp[k]  = 0.0f;
        }

        const uint32_t* pcu = (const uint32_t*)(bfb + BO_VC + l * BATCH + jc * 256);
        const uint32_t* pmu = (const uint32_t*)(bfb + BO_VM + l * BATCH + jc * 256);
        const uint32_t* peu = (const uint32_t*)(bfb + BO_TE + l * BATCH + jc * 256);

        #pragma unroll 4
        for (int jj = 0; jj < 128; ++jj) {   // 128 dwords = 256 j (pairs)
            uint32_t dc = pcu[jj], dm = pmu[jj], de = peu[jj];
            v2f cc = { bflo(dc), bfhi(dc) };
            v2f mm = { bflo(dm), bfhi(dm) };
            v2f ee = { bflo(de), bfhi(de) };
            #pragma unroll
            for (int k = 0; k < 8; ++k) {
                v2f e = __builtin_elementwise_fma(z2p[k], cc,
                          __builtin_elementwise_fma(n2p[k], mm, ee));
                v2f x;
                x.x = __builtin_amdgcn_exp2f(e.x);
                x.y = __builtin_amdgcn_exp2f(e.y);
                sp[k] += x;
            }
        }

        float* PPS = ws + OFF_PPS + l * BATCH;
        #pragma unroll
        for (int k = 0; k < 8; ++k)
            atomicAdd(&PPS[t + 256 * k], sp[k].x + sp[k].y);
    } else {
        // row path: 8 i per block, 4 j per thread over a j-half
        int bx2 = bx - DIMB;
        int ib8 = bx2 >> 1, ph = bx2 & 1;
        int i0 = ib8 * 8;
        int jb = ph * 1024 + 4 * t;
        int lane = t & 63, w = t >> 6;

        float r[8][4];
        #pragma unroll
        for (int i = 0; i < 8; ++i)
            r[i][0] = r[i][1] = r[i][2] = r[i][3] = 0.0f;

        for (int l = 0; l < LATENT; ++l) {
            const uint32_t* pc = (const uint32_t*)(bfb + BO_VC + l * BATCH);
            const uint32_t* pm = (const uint32_t*)(bfb + BO_VM + l * BATCH);
            uint32_t ca = pc[jb >> 1], cb = pc[(jb >> 1) + 1];
            uint32_t ma = pm[jb >> 1], mb = pm[(jb >> 1) + 1];
            float v0x = bflo(ca), v0y = bfhi(ca), v0z = bflo(cb), v0w = bfhi(cb);
            float v1x = bflo(ma), v1y = bfhi(ma), v1z = bflo(mb), v1w = bfhi(mb);

            const uint32_t* uz = (const uint32_t*)(bfb + BO_UZ + l * BATCH);  // uniform
            const uint32_t* un = (const uint32_t*)(bfb + BO_UN + l * BATCH);  // uniform
            #pragma unroll
            for (int h = 0; h < 4; ++h) {
                uint32_t dz = uz[(i0 >> 1) + h];
                uint32_t dn = un[(i0 >> 1) + h];
                float a0 = bflo(dz), a1 = bfhi(dz);
                float b0 = bflo(dn), b1 = bfhi(dn);
                int i = 2 * h;
                r[i][0] = fmaf(a0, v0x, fmaf(b0, v1x, r[i][0]));
                r[i][1] = fmaf(a0, v0y, fmaf(b0, v1y, r[i][1]));
                r[i][2] = fmaf(a0, v0z, fmaf(b0, v1z, r[i][2]));
                r[i][3] = fmaf(a0, v0w, fmaf(b0, v1w, r[i][3]));
                r[i+1][0] = fmaf(a1, v0x, fmaf(b1, v1x, r[i+1][0]));
                r[i+1][1] = fmaf(a1, v0y, fmaf(b1, v1y, r[i+1][1]));
                r[i+1][2] = fmaf(a1, v0z, fmaf(b1, v1z, r[i+1][2]));
                r[i+1][3] = fmaf(a1, v0w, fmaf(b1, v1w, r[i+1][3]));
            }
        }

        float4 ce4 = *(const float4*)(ws + OFF_CE + jb);
        #pragma unroll
        for (int i = 0; i < 8; ++i) {
            float rc0 = r[i][0] + ce4.x, rc1 = r[i][1] + ce4.y;
            float rc2 = r[i][2] + ce4.z, rc3 = r[i][3] + ce4.w;
            float M = fmaxf(fmaxf(rc0, rc1), fmaxf(rc2, rc3));
            float S = __builtin_amdgcn_exp2f(rc0 - M) + __builtin_amdgcn_exp2f(rc1 - M)
                    + __builtin_amdgcn_exp2f(rc2 - M) + __builtin_amdgcn_exp2f(rc3 - M);
            #pragma unroll
            for (int off = 32; off > 0; off >>= 1) {
                float Mo = __shfl_xor(M, off, 64);
                float So = __shfl_xor(S, off, 64);
                float mn = fmaxf(M, Mo);
                S = S * __builtin_amdgcn_exp2f(M - mn) + So * __builtin_amdgcn_exp2f(Mo - mn);
                M = mn;
            }
            if (lane == 0) { RMs[i][w] = M; RSs[i][w] = S; }
        }
        __syncthreads();
        if (t < 8) {
            float M = RMs[t][0], S = RSs[t][0];
            #pragma unroll
            for (int w2 = 1; w2 < 4; ++w2) {
                float Mo = RMs[t][w2], So = RSs[t][w2];
                float mn = fmaxf(M, Mo);
                S = S * __builtin_amdgcn_exp2f(M - mn) + So * __builtin_amdgcn_exp2f(Mo - mn);
                M = mn;
            }
            ws[OFF_RMP + ph * BATCH + i0 + t] = M;
            ws[OFF_RSP + ph * BATCH + i0 + t] = S;
        }
    }
}

// Flat reduction: tc = sum_i lqz_i - sum_{l,i} log2(PPS[l][i]); kl = sum KLP.
__global__ __launch_bounds__(256) void finalize_kernel(float* __restrict__ ws) {
    __shared__ float s_tc[256];
    __shared__ float s_kl[256];
    int t = threadIdx.x;
    int gid = blockIdx.x * 256 + t;

    float acc = 0.0f, kl = 0.0f;
    #pragma unroll
    for (int k = 0; k < 4; ++k) {
        int f = gid + 32768 * k;          // 0..131071 == l*2048+i
        acc -= __builtin_amdgcn_logf(ws[OFF_PPS + f]);
    }

    if (gid < BATCH) {
        int i = gid;
        float M0 = ws[OFF_RMP + i], M1 = ws[OFF_RMP + BATCH + i];
        float S0 = ws[OFF_RSP + i], S1 = ws[OFF_RSP + BATCH + i];
        float mn = fmaxf(M0, M1);
        acc += mn + __builtin_amdgcn_logf(
            S0 * __builtin_amdgcn_exp2f(M0 - mn) + S1 * __builtin_amdgcn_exp2f(M1 - mn));
        kl = ws[OFF_KLP + i];
    }

    s_tc[t] = acc; s_kl[t] = kl;
    __syncthreads();
    for (int s = 128; s > 0; s >>= 1) {
        if (t < s) { s_tc[t] += s_tc[t + s]; s_kl[t] += s_kl[t + s]; }
        __syncthreads();
    }
    if (t == 0) {
        atomicAdd(&ws[OFF_PART + 0], s_tc[0]);
        atomicAdd(&ws[OFF_PART + 1], s_kl[0]);
    }
}

__global__ void assemble_kernel(const float* __restrict__ ws,
                                float* __restrict__ out) {
    if (threadIdx.x == 0) {
        float tc = ws[OFF_PART + 0];
        float kl = ws[OFF_PART + 1];
        out[0] = BETA_M1 * (LN2 * tc / (float)BATCH) + 0.5f * (kl / (float)BATCH);
    }
}

extern "C" void kernel_launch(void* const* d_in, const int* in_sizes, int n_in,
                              void* d_out, int out_size, void* d_ws, size_t ws_size,
                              hipStream_t stream) {
    const float* z        = (const float*)d_in[0];
    const float* z_mean   = (const float*)d_in[1];
    const float* z_logvar = (const float*)d_in[2];
    float* out = (float*)d_out;
    float* ws  = (float*)d_ws;

    precompute_kernel<<<128, 256, 0, stream>>>(z, z_mean, z_logvar, ws);
    main_kernel<<<DIMB + ROWB, 256, 0, stream>>>(ws);
    finalize_kernel<<<128, 256, 0, stream>>>(ws);
    assemble_kernel<<<1, 64, 0, stream>>>(ws, out);
}